// Round 2
// baseline (1224.547 us; speedup 1.0000x reference)
//
#include <hip/hip_runtime.h>
#include <hip/hip_bf16.h>
#include <stdint.h>

// ---------------- problem constants ----------------
#define B_     2
#define T_     8192
#define D_     1024
#define H_     8
#define DH     128          // head dim
#define RTOT   (B_*T_)      // 16384 rows
#define NSC    16           // superchunks per batch (512 rows each)
#define NCHUNK 8            // 64-row chunks per superchunk

typedef __attribute__((ext_vector_type(8))) short bf16x8;   // MFMA A/B frag (8 bf16)
typedef __attribute__((ext_vector_type(4))) float f32x4;    // MFMA C/D frag

// async global->LDS, 16B per lane (LDS dest = wave-uniform base + lane*16)
__device__ __forceinline__ void gload16(void* lds, const void* g) {
  __builtin_amdgcn_global_load_lds(
      (const __attribute__((address_space(1))) unsigned int*)g,
      (__attribute__((address_space(3))) unsigned int*)lds, 16, 0, 0);
}

__device__ __forceinline__ short bf16bits(float v) {
  __hip_bfloat16 h = __float2bfloat16(v);
  return *reinterpret_cast<short*>(&h);
}
__device__ __forceinline__ float bf16val(short s) {
  __hip_bfloat16 h = *reinterpret_cast<__hip_bfloat16*>(&s);
  return __bfloat162float(h);
}

// ---------------- fp32 -> bf16 hi/lo split (weights only, 1M elems each) ----------------
__global__ void split_hl(const float* __restrict__ x, __hip_bfloat16* __restrict__ hi,
                         __hip_bfloat16* __restrict__ lo, int n) {
  int stride = gridDim.x * blockDim.x;
  for (int i = blockIdx.x * blockDim.x + threadIdx.x; i < n; i += stride) {
    float v = x[i];
    __hip_bfloat16 h = __float2bfloat16(v);
    hi[i] = h;
    lo[i] = __float2bfloat16(v - __bfloat162float(h));
  }
}

// ---------------- GEMM: C[i,j] = sum_d A[i,d]*B[j,d] ----------------
// A: M x K f32 (staged f32 to LDS, hi/lo-split in registers), B: N x K bf16 hi/lo,
// C: M x N f32. 128x128 tile, BK=64, 4 waves (2x2), 16x16x32 MFMA, 3-term hi/lo
// product (~2^-18 rel err vs fp32). LDS 64 KiB -> 2 blocks/CU.
__global__ __launch_bounds__(256, 2) void gemm_f32a(
    const float* __restrict__ A, const __hip_bfloat16* __restrict__ Bh,
    const __hip_bfloat16* __restrict__ Bl, float* __restrict__ C, int M, int N, int K)
{
  __shared__ __align__(16) float          sAf[128*64];   // 32 KiB, rows 256 B, swz ^(r&7)<<4
  __shared__ __align__(16) __hip_bfloat16 sBh[128*64];   // 16 KiB, rows 128 B, swz ^(r&7)<<4
  __shared__ __align__(16) __hip_bfloat16 sBl[128*64];   // 16 KiB

  const int tid  = threadIdx.x;
  const int lane = tid & 63;
  const int wave = tid >> 6;
  const int wr = (wave >> 1) * 64;
  const int wc = (wave & 1) * 64;
  const int row0 = blockIdx.x * 128;
  const int col0 = blockIdx.y * 128;

  f32x4 acc[4][4];
  #pragma unroll
  for (int i = 0; i < 4; ++i)
    #pragma unroll
    for (int j = 0; j < 4; ++j) acc[i][j] = (f32x4){0.f, 0.f, 0.f, 0.f};

  for (int k0 = 0; k0 < K; k0 += 64) {
    // stage A tile (f32, 32 KiB): 8 segs; linear LDS dest, inverse-swizzled source
    #pragma unroll
    for (int seg = 0; seg < 8; ++seg) {
      const int p = tid * 16 + seg * 4096;
      const int r = p >> 8;                       // 256 B per row
      const int q = (p & 255) ^ ((r & 7) << 4);
      gload16((char*)sAf + p, (const char*)A + ((size_t)(row0 + r) * K + k0) * 4 + q);
    }
    // stage B hi/lo tiles (bf16, 16 KiB each): 4 segs each
    #pragma unroll
    for (int seg = 0; seg < 4; ++seg) {
      const int p = tid * 16 + seg * 4096;
      const int r = p >> 7;                       // 128 B per row
      const int q = (p & 127) ^ ((r & 7) << 4);
      const size_t gb = (size_t)(col0 + r) * K * 2 + (size_t)(2 * k0 + q);
      gload16((char*)sBh + p, (const char*)Bh + gb);
      gload16((char*)sBl + p, (const char*)Bl + gb);
    }
    __syncthreads();

    #pragma unroll
    for (int kk = 0; kk < 2; ++kk) {
      bf16x8 ah[4], al[4], bh[4], bl[4];
      #pragma unroll
      for (int mi = 0; mi < 4; ++mi) {
        const int r = wr + mi * 16 + (lane & 15);
        const int g0p = kk * 8 + ((lane >> 4) << 1);       // 16B-granule index (pre-swz)
        const int g0 = g0p ^ (r & 7), g1 = (g0p + 1) ^ (r & 7);
        const f32x4 x0 = *(const f32x4*)&sAf[r * 64 + (g0 << 2)];
        const f32x4 x1 = *(const f32x4*)&sAf[r * 64 + (g1 << 2)];
        #pragma unroll
        for (int e = 0; e < 4; ++e) {
          const float v0 = x0[e], v1 = x1[e];
          const short h0 = bf16bits(v0), h1 = bf16bits(v1);
          ah[mi][e] = h0;     ah[mi][e + 4] = h1;
          al[mi][e] = bf16bits(v0 - bf16val(h0));
          al[mi][e + 4] = bf16bits(v1 - bf16val(h1));
        }
      }
      #pragma unroll
      for (int ni = 0; ni < 4; ++ni) {
        const int r = wc + ni * 16 + (lane & 15);
        const int off = ((r << 7) + kk * 64 + ((lane >> 4) << 4)) ^ ((r & 7) << 4);
        bh[ni] = *(const bf16x8*)((const char*)sBh + off);
        bl[ni] = *(const bf16x8*)((const char*)sBl + off);
      }
      #pragma unroll
      for (int mi = 0; mi < 4; ++mi)
        #pragma unroll
        for (int ni = 0; ni < 4; ++ni) {
          acc[mi][ni] = __builtin_amdgcn_mfma_f32_16x16x32_bf16(al[mi], bh[ni], acc[mi][ni], 0, 0, 0);
          acc[mi][ni] = __builtin_amdgcn_mfma_f32_16x16x32_bf16(ah[mi], bl[ni], acc[mi][ni], 0, 0, 0);
          acc[mi][ni] = __builtin_amdgcn_mfma_f32_16x16x32_bf16(ah[mi], bh[ni], acc[mi][ni], 0, 0, 0);
        }
    }
    __syncthreads();
  }

  // epilogue: C/D layout col=lane&15, row=(lane>>4)*4+reg (m89-verified)
  #pragma unroll
  for (int mi = 0; mi < 4; ++mi) {
    const int rb = row0 + wr + mi * 16 + ((lane >> 4) << 2);
    #pragma unroll
    for (int ni = 0; ni < 4; ++ni) {
      const int c = col0 + wc + ni * 16 + (lane & 15);
      #pragma unroll
      for (int rg = 0; rg < 4; ++rg)
        C[(size_t)(rb + rg) * N + c] = acc[mi][ni][rg];
    }
  }
}

// ---------------- Hadamard feature map, IN-PLACE: x <- (x@W1^T+b1)*(x@W2^T+b2) per head ----------------
// Block owns a disjoint 64-row x 1-head slice: loads it to LDS first, writes it back last.
__global__ __launch_bounds__(256) void featuremap(
    float* XP, const float* __restrict__ W1, const float* __restrict__ B1v,
    const float* __restrict__ W2, const float* __restrict__ B2v)
{
  __shared__ float sX[64 * 129];
  __shared__ float sW1[128 * 33];
  __shared__ float sW2[128 * 33];
  const int tid = threadIdx.x;
  const int r0 = blockIdx.x * 64;
  const int h  = blockIdx.y;
  const int tx = tid & 15, ty = tid >> 4;

  for (int idx = tid; idx < 64 * 128; idx += 256) {
    int r = idx >> 7, c = idx & 127;
    sX[r * 129 + c] = XP[(size_t)(r0 + r) * D_ + h * DH + c];
  }

  float a1[4][8] = {}, a2[4][8] = {};
  for (int kt = 0; kt < 4; ++kt) {
    __syncthreads();
    for (int idx = tid; idx < 128 * 32; idx += 256) {
      int j = idx >> 5, kk = idx & 31;
      sW1[j * 33 + kk] = W1[j * DH + kt * 32 + kk];
      sW2[j * 33 + kk] = W2[j * DH + kt * 32 + kk];
    }
    __syncthreads();
    for (int kk = 0; kk < 32; ++kk) {
      float xv[4];
      #pragma unroll
      for (int i = 0; i < 4; ++i) xv[i] = sX[(ty * 4 + i) * 129 + kt * 32 + kk];
      #pragma unroll
      for (int j = 0; j < 8; ++j) {
        float w1 = sW1[(tx + 16 * j) * 33 + kk];
        float w2 = sW2[(tx + 16 * j) * 33 + kk];
        #pragma unroll
        for (int i = 0; i < 4; ++i) {
          a1[i][j] = fmaf(xv[i], w1, a1[i][j]);
          a2[i][j] = fmaf(xv[i], w2, a2[i][j]);
        }
      }
    }
  }
  #pragma unroll
  for (int j = 0; j < 8; ++j) {
    const int col = tx + 16 * j;
    const float b1 = B1v[col], b2 = B2v[col];
    #pragma unroll
    for (int i = 0; i < 4; ++i)
      XP[(size_t)(r0 + ty * 4 + i) * D_ + h * DH + col] = (a1[i][j] + b1) * (a2[i][j] + b2);
  }
}

// ---------------- superchunk kv totals: SKV[b,h,sc] = sum_{512 rows} k^T v (128x128) ----------------
__global__ __launch_bounds__(256, 2) void skv_kernel(
    const float* __restrict__ PK, const float* __restrict__ V, float* __restrict__ SKV)
{
  __shared__ __align__(16) float sk[64 * 128];
  __shared__ __align__(16) float sv[64 * 128];
  const int tid = threadIdx.x;
  const int tx = tid & 15, ty = tid >> 4;
  const int sc = blockIdx.x, h = blockIdx.y, b = blockIdx.z;
  const size_t R0 = (size_t)b * T_ + sc * 512;

  f32x4 acc[8][2];
  #pragma unroll
  for (int i = 0; i < 8; ++i)
    #pragma unroll
    for (int g = 0; g < 2; ++g) acc[i][g] = (f32x4){0.f, 0.f, 0.f, 0.f};

  for (int sub = 0; sub < 8; ++sub) {
    __syncthreads();
    for (int i4 = tid; i4 < 2048; i4 += 256) {
      const int idx = i4 * 4;
      const int r = idx >> 7, col = idx & 127;
      const size_t gofs = (R0 + sub * 64 + r) * D_ + h * DH + col;
      *(f32x4*)&sk[idx] = *(const f32x4*)&PK[gofs];
      *(f32x4*)&sv[idx] = *(const f32x4*)&V[gofs];
    }
    __syncthreads();
    for (int c = 0; c < 64; ++c) {
      float kv[8];
      #pragma unroll
      for (int i = 0; i < 8; ++i) kv[i] = sk[c * 128 + ty + 16 * i];
      const f32x4 v0 = *(const f32x4*)&sv[c * 128 + tx * 4];
      const f32x4 v1 = *(const f32x4*)&sv[c * 128 + 64 + tx * 4];
      #pragma unroll
      for (int i = 0; i < 8; ++i)
        #pragma unroll
        for (int j = 0; j < 4; ++j) {
          acc[i][0][j] = fmaf(kv[i], v0[j], acc[i][0][j]);
          acc[i][1][j] = fmaf(kv[i], v1[j], acc[i][1][j]);
        }
    }
  }
  float* outp = SKV + ((size_t)(b * H_ + h) * NSC + sc) * 16384;
  #pragma unroll
  for (int i = 0; i < 8; ++i)
    #pragma unroll
    for (int g = 0; g < 2; ++g)
      *(f32x4*)&outp[(ty + 16 * i) * 128 + g * 64 + tx * 4] = acc[i][g];
}

// ---------------- fused chunked linear attention + RMSNorm, o written in-place over phi_q ----------------
// Block per (b,h,sc): S[128][128] in LDS initialized from prior superchunk totals, then
// 8 sequential chunks: A=qk^T (tril incl diag) -> o = A@v + q@S (v in 2 halves) ->
// S += k^T v -> RMSNorm(o)*rmsw written f32 in-place. LDS = 160 KiB exactly.
__global__ __launch_bounds__(256, 1) void fused_attn(
    const float* PQ, const float* PK, const float* V,
    const float* __restrict__ SKV, const float* __restrict__ rmsw, float* O)
{
  __shared__ __align__(16) float lds[40960];   // 160 KiB
  float* sS  = lds;            // [k 128][v 128]
  float* sQt = lds + 16384;    // [k 128][c 64]  (transposed, pre-scaled)
  float* sKt = lds + 24576;    // [k 128][c 64]
  float* sV  = lds + 32768;    // [c 64][v 64]   (current half)
  float* sA  = lds + 36864;    // [c 64][s 64]

  const int tid = threadIdx.x;
  const int tx = tid & 15, ty = tid >> 4;
  const int sc = blockIdx.x, h = blockIdx.y, b = blockIdx.z;
  const size_t R0 = (size_t)b * T_ + sc * 512;
  const float qscale = 0.08838834764831843f;   // 128^-0.5

  f32x4 rw[2];
  #pragma unroll
  for (int g = 0; g < 2; ++g) rw[g] = *(const f32x4*)&rmsw[g * 64 + tx * 4];

  // S = sum of prior superchunk kv totals (exclusive)
  {
    const float* base = SKV + (size_t)(b * H_ + h) * NSC * 16384;
    for (int i4 = tid; i4 < 4096; i4 += 256) {
      f32x4 s = (f32x4){0.f, 0.f, 0.f, 0.f};
      for (int p = 0; p < sc; ++p) {
        const f32x4 t = *(const f32x4*)&base[(size_t)p * 16384 + i4 * 4];
        s.x += t.x; s.y += t.y; s.z += t.z; s.w += t.w;
      }
      *(f32x4*)&lds[i4 * 4] = s;
    }
  }
  __syncthreads();

  for (int m = 0; m < NCHUNK; ++m) {
    const size_t rbase = R0 + m * 64;
    // stage q (scaled) and k, transposed [k][c]
    for (int i4 = tid; i4 < 2048; i4 += 256) {
      const int idx = i4 * 4;
      const int c = idx >> 7, k0 = idx & 127;
      const size_t gofs = (rbase + c) * D_ + h * DH + k0;
      const f32x4 qv = *(const f32x4*)&PQ[gofs];
      const f32x4 kv = *(const f32x4*)&PK[gofs];
      #pragma unroll
      for (int e = 0; e < 4; ++e) {
        sQt[(k0 + e) * 64 + c] = qv[e] * qscale;
        sKt[(k0 + e) * 64 + c] = kv[e];
      }
    }
    __syncthreads();

    // A = qc @ kc^T, tril mask (s <= c)
    float a[4][4] = {};
    for (int k = 0; k < 128; ++k) {
      const f32x4 qv = *(const f32x4*)&sQt[k * 64 + ty * 4];
      const f32x4 kv = *(const f32x4*)&sKt[k * 64 + tx * 4];
      #pragma unroll
      for (int i = 0; i < 4; ++i)
        #pragma unroll
        for (int j = 0; j < 4; ++j) a[i][j] = fmaf(qv[i], kv[j], a[i][j]);
    }
    #pragma unroll
    for (int i = 0; i < 4; ++i) {
      f32x4 row;
      #pragma unroll
      for (int j = 0; j < 4; ++j) row[j] = (tx * 4 + j <= ty * 4 + i) ? a[i][j] : 0.f;
      *(f32x4*)&sA[(ty * 4 + i) * 64 + tx * 4] = row;
    }

    float o[2][4][4];
    #pragma unroll
    for (int g = 0; g < 2; ++g)
      #pragma unroll
      for (int i = 0; i < 4; ++i)
        #pragma unroll
        for (int j = 0; j < 4; ++j) o[g][i][j] = 0.f;

    for (int half = 0; half < 2; ++half) {
      __syncthreads();                     // sA written / sV free to overwrite
      for (int i4 = tid; i4 < 1024; i4 += 256) {
        const int idx = i4 * 4;
        const int c = idx >> 6, v0 = idx & 63;
        *(f32x4*)&sV[idx] = *(const f32x4*)&V[(rbase + c) * D_ + h * DH + half * 64 + v0];
      }
      __syncthreads();

      // o_half = A @ vc_half + qc @ S_half
      for (int s4 = 0; s4 < 16; ++s4) {
        f32x4 av[4];
        #pragma unroll
        for (int i = 0; i < 4; ++i) av[i] = *(const f32x4*)&sA[(ty * 4 + i) * 64 + s4 * 4];
        #pragma unroll
        for (int e = 0; e < 4; ++e) {
          const f32x4 vv = *(const f32x4*)&sV[(s4 * 4 + e) * 64 + tx * 4];
          #pragma unroll
          for (int i = 0; i < 4; ++i)
            #pragma unroll
            for (int j = 0; j < 4; ++j) o[half][i][j] = fmaf(av[i][e], vv[j], o[half][i][j]);
        }
      }
      for (int k = 0; k < 128; ++k) {
        const f32x4 qv = *(const f32x4*)&sQt[k * 64 + ty * 4];
        const f32x4 sv = *(const f32x4*)&sS[k * 128 + half * 64 + tx * 4];
        #pragma unroll
        for (int i = 0; i < 4; ++i)
          #pragma unroll
          for (int j = 0; j < 4; ++j) o[half][i][j] = fmaf(qv[i], sv[j], o[half][i][j]);
      }
      __syncthreads();                     // all S reads done before update writes

      // S_half += kc^T @ vc_half (thread owns k=ty+16i, v=half*64+tx*4+j)
      f32x4 Sacc[8];
      #pragma unroll
      for (int i = 0; i < 8; ++i) Sacc[i] = *(const f32x4*)&sS[(ty + 16 * i) * 128 + half * 64 + tx * 4];
      for (int c = 0; c < 64; ++c) {
        const f32x4 vv = *(const f32x4*)&sV[c * 64 + tx * 4];
        float kc[8];
        #pragma unroll
        for (int i = 0; i < 8; ++i) kc[i] = sKt[(ty + 16 * i) * 64 + c];
        #pragma unroll
        for (int i = 0; i < 8; ++i)
          #pragma unroll
          for (int j = 0; j < 4; ++j) Sacc[i][j] = fmaf(kc[i], vv[j], Sacc[i][j]);
      }
      #pragma unroll
      for (int i = 0; i < 8; ++i) *(f32x4*)&sS[(ty + 16 * i) * 128 + half * 64 + tx * 4] = Sacc[i];
    }

    // RMSNorm over 128 cols (16 tx lanes per row are wave-consecutive) + in-place write
    #pragma unroll
    for (int i = 0; i < 4; ++i) {
      float ss = 0.f;
      #pragma unroll
      for (int g = 0; g < 2; ++g)
        #pragma unroll
        for (int j = 0; j < 4; ++j) ss += o[g][i][j] * o[g][i][j];
      ss += __shfl_xor(ss, 1); ss += __shfl_xor(ss, 2);
      ss += __shfl_xor(ss, 4); ss += __shfl_xor(ss, 8);
      const float inv = 1.f / sqrtf(ss * (1.f / 128.f) + 1e-5f);
      #pragma unroll
      for (int g = 0; g < 2; ++g) {
        f32x4 ov;
        #pragma unroll
        for (int j = 0; j < 4; ++j) ov[j] = o[g][i][j] * inv * rw[g][j];
        *(f32x4*)&O[(rbase + ty * 4 + i) * D_ + h * DH + g * 64 + tx * 4] = ov;
      }
    }
    __syncthreads();                       // protect next chunk's sQt/sKt staging
  }
}

// ---------------- host launch ----------------
extern "C" void kernel_launch(void* const* d_in, const int* in_sizes, int n_in,
                              void* d_out, int out_size, void* d_ws, size_t ws_size,
                              hipStream_t stream) {
  const float* hs = (const float*)d_in[0];
  const float* wsrc[4] = {(const float*)d_in[2], (const float*)d_in[3],
                          (const float*)d_in[4], (const float*)d_in[5]};  // q_w,k_w,v_w,o_w
  const float* fmq_w1 = (const float*)d_in[6];
  const float* fmq_b1 = (const float*)d_in[7];
  const float* fmq_w2 = (const float*)d_in[8];
  const float* fmq_b2 = (const float*)d_in[9];
  const float* fmk_w1 = (const float*)d_in[10];
  const float* fmk_b1 = (const float*)d_in[11];
  const float* fmk_w2 = (const float*)d_in[12];
  const float* fmk_b2 = (const float*)d_in[13];
  const float* rmsw   = (const float*)d_in[14];
  float* out = (float*)d_out;

  // workspace map — 160 MB total:
  //  [0,64)    q -> phi_q (in-place) -> onorm (in-place)   f32
  //  [64,128)  k -> phi_k (in-place)                       f32
  //  [128,144) weight bf16 hi/lo splits (4 x 4 MB)
  //  [144,160) SKV superchunk totals                       f32
  // v lives in d_out (dead before the final GEMM overwrites it).
  char* ws = (char*)d_ws;
  const size_t MB = 1ull << 20;
  float* q   = (float*)ws;
  float* k   = (float*)(ws + 64 * MB);
  __hip_bfloat16* w_h[4]; __hip_bfloat16* w_l[4];
  for (int i = 0; i < 4; ++i) {
    w_h[i] = (__hip_bfloat16*)(ws + 128 * MB + (size_t)i * 4 * MB);
    w_l[i] = (__hip_bfloat16*)(ws + 128 * MB + (size_t)i * 4 * MB + 2 * MB);
  }
  float* SKV = (float*)(ws + 144 * MB);
  float* v   = (float*)d_out;

  // 1) weight hi/lo splits
  for (int i = 0; i < 4; ++i)
    split_hl<<<512, 256, 0, stream>>>(wsrc[i], w_h[i], w_l[i], D_ * D_);

  // 2) q/k/v projections (A = hs f32, split in-kernel)
  dim3 gg(RTOT / 128, D_ / 128);
  gemm_f32a<<<gg, 256, 0, stream>>>(hs, w_h[0], w_l[0], q, RTOT, D_, D_);
  gemm_f32a<<<gg, 256, 0, stream>>>(hs, w_h[1], w_l[1], k, RTOT, D_, D_);
  gemm_f32a<<<gg, 256, 0, stream>>>(hs, w_h[2], w_l[2], v, RTOT, D_, D_);

  // 3) Hadamard feature maps, in-place
  featuremap<<<dim3(RTOT / 64, H_), 256, 0, stream>>>(q, fmq_w1, fmq_b1, fmq_w2, fmq_b2);
  featuremap<<<dim3(RTOT / 64, H_), 256, 0, stream>>>(k, fmk_w1, fmk_b1, fmk_w2, fmk_b2);

  // 4) superchunk kv totals
  skv_kernel<<<dim3(NSC, H_, B_), 256, 0, stream>>>(k, v, SKV);

  // 5) fused chunked attention + RMSNorm (writes normalized o in-place over q)
  fused_attn<<<dim3(NSC, H_, B_), 256, 0, stream>>>(q, k, v, SKV, rmsw, q);

  // 6) output projection
  gemm_f32a<<<gg, 256, 0, stream>>>(q, w_h[3], w_l[3], out, RTOT, D_, D_);
}

// Round 3
// 955.592 us; speedup vs baseline: 1.2815x; 1.2815x over previous
//
#include <hip/hip_runtime.h>
#include <hip/hip_bf16.h>
#include <stdint.h>

// ---------------- problem constants ----------------
#define B_     2
#define T_     8192
#define D_     1024
#define H_     8
#define DH     128          // head dim
#define RTOT   (B_*T_)      // 16384 rows
#define NSC    16           // superchunks per batch (512 rows each)
#define NCHUNK 8            // 64-row chunks per superchunk

typedef __attribute__((ext_vector_type(8))) short bf16x8;   // MFMA A/B frag (8 bf16)
typedef __attribute__((ext_vector_type(4))) float f32x4;    // MFMA C/D frag

// async global->LDS, 16B per lane (LDS dest = wave-uniform base + lane*16)
__device__ __forceinline__ void gload16(void* lds, const void* g) {
  __builtin_amdgcn_global_load_lds(
      (const __attribute__((address_space(1))) unsigned int*)g,
      (__attribute__((address_space(3))) unsigned int*)lds, 16, 0, 0);
}

__device__ __forceinline__ short bf16bits(float v) {
  __hip_bfloat16 h = __float2bfloat16(v);
  return *reinterpret_cast<short*>(&h);
}
__device__ __forceinline__ float bf16val(short s) {
  __hip_bfloat16 h = *reinterpret_cast<__hip_bfloat16*>(&s);
  return __bfloat162float(h);
}

// ---------------- fp32 -> bf16 hi/lo split (weights) ----------------
__global__ void split_hl(const float* __restrict__ x, __hip_bfloat16* __restrict__ hi,
                         __hip_bfloat16* __restrict__ lo, int n) {
  int stride = gridDim.x * blockDim.x;
  for (int i = blockIdx.x * blockDim.x + threadIdx.x; i < n; i += stride) {
    float v = x[i];
    __hip_bfloat16 h = __float2bfloat16(v);
    hi[i] = h;
    lo[i] = __float2bfloat16(v - __bfloat162float(h));
  }
}

// concat W1 (rows 0..127) and W2 (rows 128..255) into one [256][128] hi/lo pair
__global__ void split_cat(const float* __restrict__ w1, const float* __restrict__ w2,
                          __hip_bfloat16* __restrict__ hi, __hip_bfloat16* __restrict__ lo) {
  int i = blockIdx.x * 256 + threadIdx.x;     // 0..32767
  float v = (i < 16384) ? w1[i] : w2[i - 16384];
  __hip_bfloat16 h = __float2bfloat16(v);
  hi[i] = h;
  lo[i] = __float2bfloat16(v - __bfloat162float(h));
}

// ---------------- GEMM: C[i,j] = sum_d A[i,d]*B[j,d] (unchanged from round 2) ----------------
__global__ __launch_bounds__(256, 2) void gemm_f32a(
    const float* __restrict__ A, const __hip_bfloat16* __restrict__ Bh,
    const __hip_bfloat16* __restrict__ Bl, float* __restrict__ C, int M, int N, int K)
{
  __shared__ __align__(16) float          sAf[128*64];
  __shared__ __align__(16) __hip_bfloat16 sBh[128*64];
  __shared__ __align__(16) __hip_bfloat16 sBl[128*64];

  const int tid  = threadIdx.x;
  const int lane = tid & 63;
  const int wave = tid >> 6;
  const int wr = (wave >> 1) * 64;
  const int wc = (wave & 1) * 64;
  const int row0 = blockIdx.x * 128;
  const int col0 = blockIdx.y * 128;

  f32x4 acc[4][4];
  #pragma unroll
  for (int i = 0; i < 4; ++i)
    #pragma unroll
    for (int j = 0; j < 4; ++j) acc[i][j] = (f32x4){0.f, 0.f, 0.f, 0.f};

  for (int k0 = 0; k0 < K; k0 += 64) {
    #pragma unroll
    for (int seg = 0; seg < 8; ++seg) {
      const int p = tid * 16 + seg * 4096;
      const int r = p >> 8;
      const int q = (p & 255) ^ ((r & 7) << 4);
      gload16((char*)sAf + p, (const char*)A + ((size_t)(row0 + r) * K + k0) * 4 + q);
    }
    #pragma unroll
    for (int seg = 0; seg < 4; ++seg) {
      const int p = tid * 16 + seg * 4096;
      const int r = p >> 7;
      const int q = (p & 127) ^ ((r & 7) << 4);
      const size_t gb = (size_t)(col0 + r) * K * 2 + (size_t)(2 * k0 + q);
      gload16((char*)sBh + p, (const char*)Bh + gb);
      gload16((char*)sBl + p, (const char*)Bl + gb);
    }
    __syncthreads();

    #pragma unroll
    for (int kk = 0; kk < 2; ++kk) {
      bf16x8 ah[4], al[4], bh[4], bl[4];
      #pragma unroll
      for (int mi = 0; mi < 4; ++mi) {
        const int r = wr + mi * 16 + (lane & 15);
        const int g0p = kk * 8 + ((lane >> 4) << 1);
        const int g0 = g0p ^ (r & 7), g1 = (g0p + 1) ^ (r & 7);
        const f32x4 x0 = *(const f32x4*)&sAf[r * 64 + (g0 << 2)];
        const f32x4 x1 = *(const f32x4*)&sAf[r * 64 + (g1 << 2)];
        #pragma unroll
        for (int e = 0; e < 4; ++e) {
          const float v0 = x0[e], v1 = x1[e];
          const short h0 = bf16bits(v0), h1 = bf16bits(v1);
          ah[mi][e] = h0;     ah[mi][e + 4] = h1;
          al[mi][e] = bf16bits(v0 - bf16val(h0));
          al[mi][e + 4] = bf16bits(v1 - bf16val(h1));
        }
      }
      #pragma unroll
      for (int ni = 0; ni < 4; ++ni) {
        const int r = wc + ni * 16 + (lane & 15);
        const int off = ((r << 7) + kk * 64 + ((lane >> 4) << 4)) ^ ((r & 7) << 4);
        bh[ni] = *(const bf16x8*)((const char*)sBh + off);
        bl[ni] = *(const bf16x8*)((const char*)sBl + off);
      }
      #pragma unroll
      for (int mi = 0; mi < 4; ++mi)
        #pragma unroll
        for (int ni = 0; ni < 4; ++ni) {
          acc[mi][ni] = __builtin_amdgcn_mfma_f32_16x16x32_bf16(al[mi], bh[ni], acc[mi][ni], 0, 0, 0);
          acc[mi][ni] = __builtin_amdgcn_mfma_f32_16x16x32_bf16(ah[mi], bl[ni], acc[mi][ni], 0, 0, 0);
          acc[mi][ni] = __builtin_amdgcn_mfma_f32_16x16x32_bf16(ah[mi], bh[ni], acc[mi][ni], 0, 0, 0);
        }
    }
    __syncthreads();
  }

  #pragma unroll
  for (int mi = 0; mi < 4; ++mi) {
    const int rb = row0 + wr + mi * 16 + ((lane >> 4) << 2);
    #pragma unroll
    for (int ni = 0; ni < 4; ++ni) {
      const int c = col0 + wc + ni * 16 + (lane & 15);
      #pragma unroll
      for (int rg = 0; rg < 4; ++rg)
        C[(size_t)(rb + rg) * N + c] = acc[mi][ni][rg];
    }
  }
}

// ---------------- MFMA featuremap: XP_h <- (X_h@W1^T+b1)*(X_h@W2^T+b2), in-place ----------------
// Block = 128 rows x 1 head. C(128x256) = X_h(128x128) @ Wcat^T(256x128), hi/lo 3-term.
// 8 waves: wr=(w>>2)*64, wc=(w&3)*64. Epilogue pairs col j with j+128 via LDS.
__global__ __launch_bounds__(512, 1) void featuremap2(
    float* XP, const __hip_bfloat16* __restrict__ Wh, const __hip_bfloat16* __restrict__ Wl,
    const float* __restrict__ B1v, const float* __restrict__ B2v)
{
  __shared__ __align__(16) char smem[98304];     // staging 96K; epilogue reuses as [128][132] f32
  float*          sAf = (float*)smem;            // [128][64] f32 (256B rows, swz)
  __hip_bfloat16* sBh = (__hip_bfloat16*)(smem + 32768);  // [256][64] bf16 (128B rows, swz)
  __hip_bfloat16* sBl = (__hip_bfloat16*)(smem + 65536);

  const int tid  = threadIdx.x;
  const int lane = tid & 63;
  const int wave = tid >> 6;
  const int wr = (wave >> 2) * 64;       // row origin (0,64)
  const int wc = (wave & 3) * 64;        // col origin (0,64,128,192)
  const int row0 = blockIdx.x * 128;
  const int h    = blockIdx.y;

  f32x4 acc[4][4];
  #pragma unroll
  for (int i = 0; i < 4; ++i)
    #pragma unroll
    for (int j = 0; j < 4; ++j) acc[i][j] = (f32x4){0.f, 0.f, 0.f, 0.f};

  for (int k0 = 0; k0 < 128; k0 += 64) {
    #pragma unroll
    for (int seg = 0; seg < 4; ++seg) {          // A: 32 KiB
      const int p = tid * 16 + seg * 8192;
      const int r = p >> 8;
      const int q = (p & 255) ^ ((r & 7) << 4);
      gload16((char*)sAf + p,
              (const char*)XP + ((size_t)(row0 + r) * D_ + h * DH + k0) * 4 + q);
    }
    #pragma unroll
    for (int seg = 0; seg < 4; ++seg) {          // B hi/lo: 32 KiB each
      const int p = tid * 16 + seg * 8192;
      const int r = p >> 7;                      // 0..255
      const int q = (p & 127) ^ ((r & 7) << 4);
      const size_t gb = (size_t)r * 256 + (size_t)(2 * k0 + q);
      gload16((char*)sBh + p, (const char*)Wh + gb);
      gload16((char*)sBl + p, (const char*)Wl + gb);
    }
    __syncthreads();

    #pragma unroll
    for (int kk = 0; kk < 2; ++kk) {
      bf16x8 ah[4], al[4], bh[4], bl[4];
      #pragma unroll
      for (int mi = 0; mi < 4; ++mi) {
        const int r = wr + mi * 16 + (lane & 15);
        const int g0p = kk * 8 + ((lane >> 4) << 1);
        const int g0 = g0p ^ (r & 7), g1 = (g0p + 1) ^ (r & 7);
        const f32x4 x0 = *(const f32x4*)&sAf[r * 64 + (g0 << 2)];
        const f32x4 x1 = *(const f32x4*)&sAf[r * 64 + (g1 << 2)];
        #pragma unroll
        for (int e = 0; e < 4; ++e) {
          const float v0 = x0[e], v1 = x1[e];
          const short h0 = bf16bits(v0), h1 = bf16bits(v1);
          ah[mi][e] = h0;     ah[mi][e + 4] = h1;
          al[mi][e] = bf16bits(v0 - bf16val(h0));
          al[mi][e + 4] = bf16bits(v1 - bf16val(h1));
        }
      }
      #pragma unroll
      for (int ni = 0; ni < 4; ++ni) {
        const int r = wc + ni * 16 + (lane & 15);
        const int off = ((r << 7) + kk * 64 + ((lane >> 4) << 4)) ^ ((r & 7) << 4);
        bh[ni] = *(const bf16x8*)((const char*)sBh + off);
        bl[ni] = *(const bf16x8*)((const char*)sBl + off);
      }
      #pragma unroll
      for (int mi = 0; mi < 4; ++mi)
        #pragma unroll
        for (int ni = 0; ni < 4; ++ni) {
          acc[mi][ni] = __builtin_amdgcn_mfma_f32_16x16x32_bf16(al[mi], bh[ni], acc[mi][ni], 0, 0, 0);
          acc[mi][ni] = __builtin_amdgcn_mfma_f32_16x16x32_bf16(ah[mi], bl[ni], acc[mi][ni], 0, 0, 0);
          acc[mi][ni] = __builtin_amdgcn_mfma_f32_16x16x32_bf16(ah[mi], bh[ni], acc[mi][ni], 0, 0, 0);
        }
    }
    __syncthreads();
  }

  // epilogue: C1 waves (wc<128) deposit a1+b1 to LDS; C2 waves multiply and store
  float* sEp = (float*)smem;                     // [128][132] f32
  if (wc < 128) {
    #pragma unroll
    for (int mi = 0; mi < 4; ++mi) {
      const int rb = wr + mi * 16 + ((lane >> 4) << 2);
      #pragma unroll
      for (int ni = 0; ni < 4; ++ni) {
        const int col = wc + ni * 16 + (lane & 15);
        const float b1 = B1v[col];
        #pragma unroll
        for (int rg = 0; rg < 4; ++rg)
          sEp[(rb + rg) * 132 + col] = acc[mi][ni][rg] + b1;
      }
    }
  }
  __syncthreads();
  if (wc >= 128) {
    #pragma unroll
    for (int mi = 0; mi < 4; ++mi) {
      const int rb = wr + mi * 16 + ((lane >> 4) << 2);
      #pragma unroll
      for (int ni = 0; ni < 4; ++ni) {
        const int c2 = wc - 128 + ni * 16 + (lane & 15);
        const float b2 = B2v[c2];
        #pragma unroll
        for (int rg = 0; rg < 4; ++rg) {
          const int row = rb + rg;
          XP[(size_t)(row0 + row) * D_ + h * DH + c2] =
              sEp[row * 132 + c2] * (acc[mi][ni][rg] + b2);
        }
      }
    }
  }
}

// ---------------- superchunk kv totals: SKV[b,h,sc] = sum_{512 rows} k^T v (128x128) ----------------
__global__ __launch_bounds__(256, 2) void skv_kernel(
    const float* __restrict__ PK, const float* __restrict__ V, float* __restrict__ SKV)
{
  __shared__ __align__(16) float sk[64 * 128];
  __shared__ __align__(16) float sv[64 * 128];
  const int tid = threadIdx.x;
  const int tx = tid & 15, ty = tid >> 4;
  const int sc = blockIdx.x, h = blockIdx.y, b = blockIdx.z;
  const size_t R0 = (size_t)b * T_ + sc * 512;

  f32x4 acc[8][2];
  #pragma unroll
  for (int i = 0; i < 8; ++i)
    #pragma unroll
    for (int g = 0; g < 2; ++g) acc[i][g] = (f32x4){0.f, 0.f, 0.f, 0.f};

  for (int sub = 0; sub < 8; ++sub) {
    __syncthreads();
    for (int i4 = tid; i4 < 2048; i4 += 256) {
      const int idx = i4 * 4;
      const int r = idx >> 7, col = idx & 127;
      const size_t gofs = (R0 + sub * 64 + r) * D_ + h * DH + col;
      *(f32x4*)&sk[idx] = *(const f32x4*)&PK[gofs];
      *(f32x4*)&sv[idx] = *(const f32x4*)&V[gofs];
    }
    __syncthreads();
    for (int c = 0; c < 64; ++c) {
      float kv[8];
      #pragma unroll
      for (int i = 0; i < 8; ++i) kv[i] = sk[c * 128 + ty + 16 * i];
      const f32x4 v0 = *(const f32x4*)&sv[c * 128 + tx * 4];
      const f32x4 v1 = *(const f32x4*)&sv[c * 128 + 64 + tx * 4];
      #pragma unroll
      for (int i = 0; i < 8; ++i)
        #pragma unroll
        for (int j = 0; j < 4; ++j) {
          acc[i][0][j] = fmaf(kv[i], v0[j], acc[i][0][j]);
          acc[i][1][j] = fmaf(kv[i], v1[j], acc[i][1][j]);
        }
    }
  }
  float* outp = SKV + ((size_t)(b * H_ + h) * NSC + sc) * 16384;
  #pragma unroll
  for (int i = 0; i < 8; ++i)
    #pragma unroll
    for (int g = 0; g < 2; ++g)
      *(f32x4*)&outp[(ty + 16 * i) * 128 + g * 64 + tx * 4] = acc[i][g];
}

// ---------------- in-place EXCLUSIVE prefix over superchunks ----------------
__global__ void skv_prefix(float* __restrict__ SKV) {
  const int e = blockIdx.x * 256 + threadIdx.x;                 // 0..16383
  float* p = SKV + (size_t)(blockIdx.z * H_ + blockIdx.y) * NSC * 16384 + e;
  float s = 0.f;
  #pragma unroll
  for (int sc = 0; sc < NSC; ++sc) {
    const float x = p[(size_t)sc * 16384];
    p[(size_t)sc * 16384] = s;
    s += x;
  }
}

// ---------------- fused chunked linear attention + RMSNorm (512 threads, conflict-free) ----------------
// Block per (b,h,sc). LDS exactly 160K: sS[128][128] + sQt[128][64] + sKt[128][64] + sV[64][128].
// Per chunk: stage q,k transposed (column-staging: lane=col -> 2-way banks) + v natural;
// A=qk^T in regs (c=ty*2+i, s=tx*4+j); A broadcast via shfl for o=A@v; o+=q@S; S+=k^T v; RMSNorm.
__global__ __launch_bounds__(512, 1) void fused_attn(
    const float* PQ, const float* PK, const float* V,
    const float* __restrict__ SKVp, const float* __restrict__ rmsw, float* O)
{
  __shared__ __align__(16) float sS [128 * 128];
  __shared__ __align__(16) float sQt[128 * 64];
  __shared__ __align__(16) float sKt[128 * 64];
  __shared__ __align__(16) float sV [64 * 128];

  const int tid  = threadIdx.x;
  const int lane = tid & 63;
  const int tx = tid & 15, ty = tid >> 4;        // ty 0..31
  const int sc = blockIdx.x, h = blockIdx.y, b = blockIdx.z;
  const size_t R0 = (size_t)b * T_ + sc * 512;
  const float qscale = 0.08838834764831843f;     // 128^-0.5

  f32x4 rw[2];
  #pragma unroll
  for (int g = 0; g < 2; ++g) rw[g] = *(const f32x4*)&rmsw[g * 64 + tx * 4];

  // S init from prefixed SKV (exclusive superchunk state)
  {
    const float* slab = SKVp + ((size_t)(b * H_ + h) * NSC + sc) * 16384;
    for (int i = tid; i < 4096; i += 512)
      *(f32x4*)&sS[i * 4] = *(const f32x4*)&slab[i * 4];
  }
  __syncthreads();

  const int cst = tid & 63;        // staging column (= lane -> conflict-free writes)
  const int kq  = tid >> 6;        // staging k-quad: k in [kq*16, kq*16+16)

  for (int m = 0; m < NCHUNK; ++m) {
    const size_t rbase = R0 + m * 64;

    // stage q (scaled) and k, transposed [k][c]
    {
      const float* qp = PQ + (rbase + cst) * D_ + h * DH + kq * 16;
      const float* kp = PK + (rbase + cst) * D_ + h * DH + kq * 16;
      #pragma unroll
      for (int t = 0; t < 4; ++t) {
        const f32x4 qv = *(const f32x4*)(qp + t * 4);
        const f32x4 kv = *(const f32x4*)(kp + t * 4);
        #pragma unroll
        for (int e = 0; e < 4; ++e) {
          const int k = kq * 16 + t * 4 + e;
          sQt[k * 64 + cst] = qv[e] * qscale;
          sKt[k * 64 + cst] = kv[e];
        }
      }
    }
    // stage v natural [c][v]
    for (int i = tid; i < 2048; i += 512) {
      const int idx = i * 4;
      const int c2 = idx >> 7, v0 = idx & 127;
      *(f32x4*)&sV[idx] = *(const f32x4*)&V[(rbase + c2) * D_ + h * DH + v0];
    }
    __syncthreads();

    // phase A: a[i][j] = A[c = ty*2+i][s = tx*4+j]
    float a[2][4] = {};
    for (int k = 0; k < 128; ++k) {
      const float2 q2 = *(const float2*)&sQt[k * 64 + ty * 2];
      const f32x4  k4 = *(const f32x4*)&sKt[k * 64 + tx * 4];
      #pragma unroll
      for (int j = 0; j < 4; ++j) {
        a[0][j] = fmaf(q2.x, k4[j], a[0][j]);
        a[1][j] = fmaf(q2.y, k4[j], a[1][j]);
      }
    }
    #pragma unroll
    for (int i = 0; i < 2; ++i)
      #pragma unroll
      for (int j = 0; j < 4; ++j)
        if (tx * 4 + j > ty * 2 + i) a[i][j] = 0.f;

    float o[2][2][4] = {};   // [i][g][j]: row c=ty*2+i, col v=g*64+tx*4+j

    // o = A @ v  (A broadcast across the 16-lane row group via shfl)
    for (int tq = 0; tq < 16; ++tq) {
      const int src = (lane & 48) | tq;
      f32x4 vv[4][2];
      #pragma unroll
      for (int j = 0; j < 4; ++j)
        #pragma unroll
        for (int g = 0; g < 2; ++g)
          vv[j][g] = *(const f32x4*)&sV[(tq * 4 + j) * 128 + g * 64 + tx * 4];
      #pragma unroll
      for (int i = 0; i < 2; ++i) {
        float av[4];
        #pragma unroll
        for (int j = 0; j < 4; ++j) av[j] = __shfl(a[i][j], src);
        #pragma unroll
        for (int j = 0; j < 4; ++j)
          #pragma unroll
          for (int g = 0; g < 2; ++g)
            #pragma unroll
            for (int jj = 0; jj < 4; ++jj)
              o[i][g][jj] = fmaf(av[j], vv[j][g][jj], o[i][g][jj]);
      }
    }

    // o += q @ S_excl
    for (int k = 0; k < 128; ++k) {
      const float2 q2 = *(const float2*)&sQt[k * 64 + ty * 2];
      #pragma unroll
      for (int g = 0; g < 2; ++g) {
        const f32x4 sv = *(const f32x4*)&sS[k * 128 + g * 64 + tx * 4];
        #pragma unroll
        for (int j = 0; j < 4; ++j) {
          o[0][g][j] = fmaf(q2.x, sv[j], o[0][g][j]);
          o[1][g][j] = fmaf(q2.y, sv[j], o[1][g][j]);
        }
      }
    }
    __syncthreads();     // all S reads complete before update

    // S += k^T @ v  (thread owns k = ty+32i, v = g*64+tx*4+j)
    {
      f32x4 Sacc[4][2];
      #pragma unroll
      for (int i = 0; i < 4; ++i)
        #pragma unroll
        for (int g = 0; g < 2; ++g)
          Sacc[i][g] = *(const f32x4*)&sS[(ty + 32 * i) * 128 + g * 64 + tx * 4];
      for (int c = 0; c < 64; ++c) {
        f32x4 vvg[2];
        #pragma unroll
        for (int g = 0; g < 2; ++g)
          vvg[g] = *(const f32x4*)&sV[c * 128 + g * 64 + tx * 4];
        float kc[4];
        #pragma unroll
        for (int i = 0; i < 4; ++i) kc[i] = sKt[(ty + 32 * i) * 64 + c];
        #pragma unroll
        for (int i = 0; i < 4; ++i)
          #pragma unroll
          for (int g = 0; g < 2; ++g)
            #pragma unroll
            for (int j = 0; j < 4; ++j)
              Sacc[i][g][j] = fmaf(kc[i], vvg[g][j], Sacc[i][g][j]);
      }
      #pragma unroll
      for (int i = 0; i < 4; ++i)
        #pragma unroll
        for (int g = 0; g < 2; ++g)
          *(f32x4*)&sS[(ty + 32 * i) * 128 + g * 64 + tx * 4] = Sacc[i][g];
    }

    // RMSNorm over 128 cols (16 tx lanes per row) + in-place write
    #pragma unroll
    for (int i = 0; i < 2; ++i) {
      float ss = 0.f;
      #pragma unroll
      for (int g = 0; g < 2; ++g)
        #pragma unroll
        for (int j = 0; j < 4; ++j) ss += o[i][g][j] * o[i][g][j];
      ss += __shfl_xor(ss, 1); ss += __shfl_xor(ss, 2);
      ss += __shfl_xor(ss, 4); ss += __shfl_xor(ss, 8);
      const float inv = 1.f / sqrtf(ss * (1.f / 128.f) + 1e-5f);
      #pragma unroll
      for (int g = 0; g < 2; ++g) {
        f32x4 ov;
        #pragma unroll
        for (int j = 0; j < 4; ++j) ov[j] = o[i][g][j] * inv * rw[g][j];
        *(f32x4*)&O[(rbase + ty * 2 + i) * D_ + h * DH + g * 64 + tx * 4] = ov;
      }
    }
    __syncthreads();     // protect next chunk's staging
  }
}

// ---------------- host launch ----------------
extern "C" void kernel_launch(void* const* d_in, const int* in_sizes, int n_in,
                              void* d_out, int out_size, void* d_ws, size_t ws_size,
                              hipStream_t stream) {
  const float* hs = (const float*)d_in[0];
  const float* wsrc[4] = {(const float*)d_in[2], (const float*)d_in[3],
                          (const float*)d_in[4], (const float*)d_in[5]};  // q_w,k_w,v_w,o_w
  const float* fmq_w1 = (const float*)d_in[6];
  const float* fmq_b1 = (const float*)d_in[7];
  const float* fmq_w2 = (const float*)d_in[8];
  const float* fmq_b2 = (const float*)d_in[9];
  const float* fmk_w1 = (const float*)d_in[10];
  const float* fmk_b1 = (const float*)d_in[11];
  const float* fmk_w2 = (const float*)d_in[12];
  const float* fmk_b2 = (const float*)d_in[13];
  const float* rmsw   = (const float*)d_in[14];
  float* out = (float*)d_out;

  // workspace map — 160 MB total (proven in round 2):
  //  [0,64)    q -> phi_q -> onorm (in-place)  f32
  //  [64,128)  k -> phi_k (in-place)           f32
  //  [128,144) big-weight bf16 hi/lo (4 x 4MB)
  //  [144,160) SKV superchunk totals (16 MB); its first 256KB transiently holds the
  //            fm-weight concat splits, consumed by featuremap2 BEFORE skv_kernel writes.
  // v lives in d_out (dead before the final GEMM overwrites it).
  char* ws = (char*)d_ws;
  const size_t MB = 1ull << 20;
  float* q = (float*)ws;
  float* k = (float*)(ws + 64 * MB);
  __hip_bfloat16* w_h[4]; __hip_bfloat16* w_l[4];
  for (int i = 0; i < 4; ++i) {
    w_h[i] = (__hip_bfloat16*)(ws + 128 * MB + (size_t)i * 4 * MB);
    w_l[i] = (__hip_bfloat16*)(ws + 128 * MB + (size_t)i * 4 * MB + 2 * MB);
  }
  float* SKV = (float*)(ws + 144 * MB);
  __hip_bfloat16* wcq_h = (__hip_bfloat16*)(ws + 144 * MB);
  __hip_bfloat16* wcq_l = (__hip_bfloat16*)(ws + 144 * MB + 64 * 1024);
  __hip_bfloat16* wck_h = (__hip_bfloat16*)(ws + 144 * MB + 128 * 1024);
  __hip_bfloat16* wck_l = (__hip_bfloat16*)(ws + 144 * MB + 192 * 1024);
  float* v = (float*)d_out;

  // 1) weight splits
  for (int i = 0; i < 4; ++i)
    split_hl<<<512, 256, 0, stream>>>(wsrc[i], w_h[i], w_l[i], D_ * D_);
  split_cat<<<128, 256, 0, stream>>>(fmq_w1, fmq_w2, wcq_h, wcq_l);
  split_cat<<<128, 256, 0, stream>>>(fmk_w1, fmk_w2, wck_h, wck_l);

  // 2) q/k/v projections
  dim3 gg(RTOT / 128, D_ / 128);
  gemm_f32a<<<gg, 256, 0, stream>>>(hs, w_h[0], w_l[0], q, RTOT, D_, D_);
  gemm_f32a<<<gg, 256, 0, stream>>>(hs, w_h[1], w_l[1], k, RTOT, D_, D_);
  gemm_f32a<<<gg, 256, 0, stream>>>(hs, w_h[2], w_l[2], v, RTOT, D_, D_);

  // 3) Hadamard feature maps (MFMA, in-place)
  featuremap2<<<dim3(RTOT / 128, H_), 512, 0, stream>>>(q, wcq_h, wcq_l, fmq_b1, fmq_b2);
  featuremap2<<<dim3(RTOT / 128, H_), 512, 0, stream>>>(k, wck_h, wck_l, fmk_b1, fmk_b2);

  // 4) superchunk kv totals + exclusive prefix (overwrites the wcat scratch: safe, stream-ordered)
  skv_kernel<<<dim3(NSC, H_, B_), 256, 0, stream>>>(k, v, SKV);
  skv_prefix<<<dim3(64, H_, B_), 256, 0, stream>>>(SKV);

  // 5) fused chunked attention + RMSNorm (writes normalized o in-place over q)
  fused_attn<<<dim3(NSC, H_, B_), 512, 0, stream>>>(q, k, v, SKV, rmsw, q);

  // 6) output projection
  gemm_f32a<<<gg, 256, 0, stream>>>(q, w_h[3], w_l[3], out, RTOT, D_, D_);
}

// Round 5
// 906.635 us; speedup vs baseline: 1.3507x; 1.0540x over previous
//
#include <hip/hip_runtime.h>
#include <hip/hip_bf16.h>
#include <stdint.h>

// ---------------- problem constants ----------------
#define B_     2
#define T_     8192
#define D_     1024
#define H_     8
#define DH     128          // head dim
#define RTOT   (B_*T_)      // 16384 rows
#define NSC    16           // superchunks per batch (512 rows each)
#define NCHUNK 8            // 64-row chunks per superchunk

typedef __attribute__((ext_vector_type(8))) short bf16x8;   // MFMA A/B frag (8 bf16)
typedef __attribute__((ext_vector_type(4))) float f32x4;    // MFMA C/D frag

// async global->LDS, 16B per lane (LDS dest = wave-uniform base + lane*16)
__device__ __forceinline__ void gload16(void* lds, const void* g) {
  __builtin_amdgcn_global_load_lds(
      (const __attribute__((address_space(1))) unsigned int*)g,
      (__attribute__((address_space(3))) unsigned int*)lds, 16, 0, 0);
}

__device__ __forceinline__ short bf16bits(float v) {
  __hip_bfloat16 h = __float2bfloat16(v);
  return *reinterpret_cast<short*>(&h);
}
__device__ __forceinline__ float bf16val(short s) {
  __hip_bfloat16 h = *reinterpret_cast<__hip_bfloat16*>(&s);
  return __bfloat162float(h);
}

// truncation hi/lo split: v = hi + lo + err, |err| <= 2^-16 |v|.
__device__ __forceinline__ void split8(const f32x4 x0, const f32x4 x1,
                                       bf16x8& hi, bf16x8& lo) {
  #pragma unroll
  for (int e = 0; e < 4; ++e) {
    const unsigned u0 = __builtin_bit_cast(unsigned, x0[e]);
    const float hf0 = __builtin_bit_cast(float, u0 & 0xFFFF0000u);
    hi[e] = (short)(u0 >> 16);
    lo[e] = (short)(__builtin_bit_cast(unsigned, x0[e] - hf0) >> 16);
    const unsigned u1 = __builtin_bit_cast(unsigned, x1[e]);
    const float hf1 = __builtin_bit_cast(float, u1 & 0xFFFF0000u);
    hi[e + 4] = (short)(u1 >> 16);
    lo[e + 4] = (short)(__builtin_bit_cast(unsigned, x1[e] - hf1) >> 16);
  }
}

// ---------------- fp32 -> bf16 hi/lo split (weights) ----------------
__global__ void split_hl(const float* __restrict__ x, __hip_bfloat16* __restrict__ hi,
                         __hip_bfloat16* __restrict__ lo, int n) {
  int stride = gridDim.x * blockDim.x;
  for (int i = blockIdx.x * blockDim.x + threadIdx.x; i < n; i += stride) {
    float v = x[i];
    __hip_bfloat16 h = __float2bfloat16(v);
    hi[i] = h;
    lo[i] = __float2bfloat16(v - __bfloat162float(h));
  }
}

// concat W1 (rows 0..127) and W2 (rows 128..255) into one [256][128] hi/lo pair
__global__ void split_cat(const float* __restrict__ w1, const float* __restrict__ w2,
                          __hip_bfloat16* __restrict__ hi, __hip_bfloat16* __restrict__ lo) {
  int i = blockIdx.x * 256 + threadIdx.x;     // 0..32767
  float v = (i < 16384) ? w1[i] : w2[i - 16384];
  __hip_bfloat16 h = __float2bfloat16(v);
  hi[i] = h;
  lo[i] = __float2bfloat16(v - __bfloat162float(h));
}

// ---------------- GEMM: C[i,j] = sum_d A[i,d]*B[j,d] ----------------
// v2 (byte-identical to round 4): wave tile 32x128; truncation bit-op split.
__global__ __launch_bounds__(256, 2) void gemm_f32a(
    const float* __restrict__ A, const __hip_bfloat16* __restrict__ Bh,
    const __hip_bfloat16* __restrict__ Bl, float* __restrict__ C, int M, int N, int K)
{
  __shared__ __align__(16) float          sAf[128*64];
  __shared__ __align__(16) __hip_bfloat16 sBh[128*64];
  __shared__ __align__(16) __hip_bfloat16 sBl[128*64];

  const int tid  = threadIdx.x;
  const int lane = tid & 63;
  const int wave = tid >> 6;
  const int wr = wave * 32;            // wave rows [wr, wr+32)
  const int row0 = blockIdx.x * 128;
  const int col0 = blockIdx.y * 128;

  f32x4 acc[2][8];
  #pragma unroll
  for (int i = 0; i < 2; ++i)
    #pragma unroll
    for (int j = 0; j < 8; ++j) acc[i][j] = (f32x4){0.f, 0.f, 0.f, 0.f};

  for (int k0 = 0; k0 < K; k0 += 64) {
    #pragma unroll
    for (int seg = 0; seg < 8; ++seg) {
      const int p = tid * 16 + seg * 4096;
      const int r = p >> 8;
      const int q = (p & 255) ^ ((r & 7) << 4);
      gload16((char*)sAf + p, (const char*)A + ((size_t)(row0 + r) * K + k0) * 4 + q);
    }
    #pragma unroll
    for (int seg = 0; seg < 4; ++seg) {
      const int p = tid * 16 + seg * 4096;
      const int r = p >> 7;
      const int q = (p & 127) ^ ((r & 7) << 4);
      const size_t gb = (size_t)(col0 + r) * K * 2 + (size_t)(2 * k0 + q);
      gload16((char*)sBh + p, (const char*)Bh + gb);
      gload16((char*)sBl + p, (const char*)Bl + gb);
    }
    __syncthreads();

    #pragma unroll
    for (int kk = 0; kk < 2; ++kk) {
      bf16x8 ah[2], al[2];
      #pragma unroll
      for (int mi = 0; mi < 2; ++mi) {
        const int r = wr + mi * 16 + (lane & 15);
        const int g0p = kk * 8 + ((lane >> 4) << 1);
        const int g0 = g0p ^ (r & 7), g1 = (g0p + 1) ^ (r & 7);
        const f32x4 x0 = *(const f32x4*)&sAf[r * 64 + (g0 << 2)];
        const f32x4 x1 = *(const f32x4*)&sAf[r * 64 + (g1 << 2)];
        split8(x0, x1, ah[mi], al[mi]);
      }
      #pragma unroll
      for (int ni = 0; ni < 8; ++ni) {
        const int r = ni * 16 + (lane & 15);
        const int off = ((r << 7) + kk * 64 + ((lane >> 4) << 4)) ^ ((r & 7) << 4);
        const bf16x8 bh = *(const bf16x8*)((const char*)sBh + off);
        const bf16x8 bl = *(const bf16x8*)((const char*)sBl + off);
        #pragma unroll
        for (int mi = 0; mi < 2; ++mi) {
          acc[mi][ni] = __builtin_amdgcn_mfma_f32_16x16x32_bf16(al[mi], bh, acc[mi][ni], 0, 0, 0);
          acc[mi][ni] = __builtin_amdgcn_mfma_f32_16x16x32_bf16(ah[mi], bl, acc[mi][ni], 0, 0, 0);
          acc[mi][ni] = __builtin_amdgcn_mfma_f32_16x16x32_bf16(ah[mi], bh, acc[mi][ni], 0, 0, 0);
        }
      }
    }
    __syncthreads();
  }

  #pragma unroll
  for (int mi = 0; mi < 2; ++mi) {
    const int rb = row0 + wr + mi * 16 + ((lane >> 4) << 2);
    #pragma unroll
    for (int ni = 0; ni < 8; ++ni) {
      const int c = col0 + ni * 16 + (lane & 15);
      #pragma unroll
      for (int rg = 0; rg < 4; ++rg)
        C[(size_t)(rb + rg) * N + c] = acc[mi][ni][rg];
    }
  }
}

// ---------------- MFMA featuremap (round-3 proven) ----------------
__global__ __launch_bounds__(512, 1) void featuremap2(
    float* XP, const __hip_bfloat16* __restrict__ Wh, const __hip_bfloat16* __restrict__ Wl,
    const float* __restrict__ B1v, const float* __restrict__ B2v)
{
  __shared__ __align__(16) char smem[98304];
  float*          sAf = (float*)smem;
  __hip_bfloat16* sBh = (__hip_bfloat16*)(smem + 32768);
  __hip_bfloat16* sBl = (__hip_bfloat16*)(smem + 65536);

  const int tid  = threadIdx.x;
  const int lane = tid & 63;
  const int wave = tid >> 6;
  const int wr = (wave >> 2) * 64;
  const int wc = (wave & 3) * 64;
  const int row0 = blockIdx.x * 128;
  const int h    = blockIdx.y;

  f32x4 acc[4][4];
  #pragma unroll
  for (int i = 0; i < 4; ++i)
    #pragma unroll
    for (int j = 0; j < 4; ++j) acc[i][j] = (f32x4){0.f, 0.f, 0.f, 0.f};

  for (int k0 = 0; k0 < 128; k0 += 64) {
    #pragma unroll
    for (int seg = 0; seg < 4; ++seg) {
      const int p = tid * 16 + seg * 8192;
      const int r = p >> 8;
      const int q = (p & 255) ^ ((r & 7) << 4);
      gload16((char*)sAf + p,
              (const char*)XP + ((size_t)(row0 + r) * D_ + h * DH + k0) * 4 + q);
    }
    #pragma unroll
    for (int seg = 0; seg < 4; ++seg) {
      const int p = tid * 16 + seg * 8192;
      const int r = p >> 7;
      const int q = (p & 127) ^ ((r & 7) << 4);
      const size_t gb = (size_t)r * 256 + (size_t)(2 * k0 + q);
      gload16((char*)sBh + p, (const char*)Wh + gb);
      gload16((char*)sBl + p, (const char*)Wl + gb);
    }
    __syncthreads();

    #pragma unroll
    for (int kk = 0; kk < 2; ++kk) {
      bf16x8 ah[4], al[4], bh[4], bl[4];
      #pragma unroll
      for (int mi = 0; mi < 4; ++mi) {
        const int r = wr + mi * 16 + (lane & 15);
        const int g0p = kk * 8 + ((lane >> 4) << 1);
        const int g0 = g0p ^ (r & 7), g1 = (g0p + 1) ^ (r & 7);
        const f32x4 x0 = *(const f32x4*)&sAf[r * 64 + (g0 << 2)];
        const f32x4 x1 = *(const f32x4*)&sAf[r * 64 + (g1 << 2)];
        #pragma unroll
        for (int e = 0; e < 4; ++e) {
          const float v0 = x0[e], v1 = x1[e];
          const short h0 = bf16bits(v0), h1 = bf16bits(v1);
          ah[mi][e] = h0;     ah[mi][e + 4] = h1;
          al[mi][e] = bf16bits(v0 - bf16val(h0));
          al[mi][e + 4] = bf16bits(v1 - bf16val(h1));
        }
      }
      #pragma unroll
      for (int ni = 0; ni < 4; ++ni) {
        const int r = wc + ni * 16 + (lane & 15);
        const int off = ((r << 7) + kk * 64 + ((lane >> 4) << 4)) ^ ((r & 7) << 4);
        bh[ni] = *(const bf16x8*)((const char*)sBh + off);
        bl[ni] = *(const bf16x8*)((const char*)sBl + off);
      }
      #pragma unroll
      for (int mi = 0; mi < 4; ++mi)
        #pragma unroll
        for (int ni = 0; ni < 4; ++ni) {
          acc[mi][ni] = __builtin_amdgcn_mfma_f32_16x16x32_bf16(al[mi], bh[ni], acc[mi][ni], 0, 0, 0);
          acc[mi][ni] = __builtin_amdgcn_mfma_f32_16x16x32_bf16(ah[mi], bl[ni], acc[mi][ni], 0, 0, 0);
          acc[mi][ni] = __builtin_amdgcn_mfma_f32_16x16x32_bf16(ah[mi], bh[ni], acc[mi][ni], 0, 0, 0);
        }
    }
    __syncthreads();
  }

  float* sEp = (float*)smem;
  if (wc < 128) {
    #pragma unroll
    for (int mi = 0; mi < 4; ++mi) {
      const int rb = wr + mi * 16 + ((lane >> 4) << 2);
      #pragma unroll
      for (int ni = 0; ni < 4; ++ni) {
        const int col = wc + ni * 16 + (lane & 15);
        const float b1 = B1v[col];
        #pragma unroll
        for (int rg = 0; rg < 4; ++rg)
          sEp[(rb + rg) * 132 + col] = acc[mi][ni][rg] + b1;
      }
    }
  }
  __syncthreads();
  if (wc >= 128) {
    #pragma unroll
    for (int mi = 0; mi < 4; ++mi) {
      const int rb = wr + mi * 16 + ((lane >> 4) << 2);
      #pragma unroll
      for (int ni = 0; ni < 4; ++ni) {
        const int c2 = wc - 128 + ni * 16 + (lane & 15);
        const float b2 = B2v[c2];
        #pragma unroll
        for (int rg = 0; rg < 4; ++rg) {
          const int row = rb + rg;
          XP[(size_t)(row0 + row) * D_ + h * DH + c2] =
              sEp[row * 132 + c2] * (acc[mi][ni][rg] + b2);
        }
      }
    }
  }
}

// ---------------- superchunk kv totals (round-3 proven) ----------------
__global__ __launch_bounds__(256, 2) void skv_kernel(
    const float* __restrict__ PK, const float* __restrict__ V, float* __restrict__ SKV)
{
  __shared__ __align__(16) float sk[64 * 128];
  __shared__ __align__(16) float sv[64 * 128];
  const int tid = threadIdx.x;
  const int tx = tid & 15, ty = tid >> 4;
  const int sc = blockIdx.x, h = blockIdx.y, b = blockIdx.z;
  const size_t R0 = (size_t)b * T_ + sc * 512;

  f32x4 acc[8][2];
  #pragma unroll
  for (int i = 0; i < 8; ++i)
    #pragma unroll
    for (int g = 0; g < 2; ++g) acc[i][g] = (f32x4){0.f, 0.f, 0.f, 0.f};

  for (int sub = 0; sub < 8; ++sub) {
    __syncthreads();
    for (int i4 = tid; i4 < 2048; i4 += 256) {
      const int idx = i4 * 4;
      const int r = idx >> 7, col = idx & 127;
      const size_t gofs = (R0 + sub * 64 + r) * D_ + h * DH + col;
      *(f32x4*)&sk[idx] = *(const f32x4*)&PK[gofs];
      *(f32x4*)&sv[idx] = *(const f32x4*)&V[gofs];
    }
    __syncthreads();
    for (int c = 0; c < 64; ++c) {
      float kv[8];
      #pragma unroll
      for (int i = 0; i < 8; ++i) kv[i] = sk[c * 128 + ty + 16 * i];
      const f32x4 v0 = *(const f32x4*)&sv[c * 128 + tx * 4];
      const f32x4 v1 = *(const f32x4*)&sv[c * 128 + 64 + tx * 4];
      #pragma unroll
      for (int i = 0; i < 8; ++i)
        #pragma unroll
        for (int j = 0; j < 4; ++j) {
          acc[i][0][j] = fmaf(kv[i], v0[j], acc[i][0][j]);
          acc[i][1][j] = fmaf(kv[i], v1[j], acc[i][1][j]);
        }
    }
  }
  float* outp = SKV + ((size_t)(b * H_ + h) * NSC + sc) * 16384;
  #pragma unroll
  for (int i = 0; i < 8; ++i)
    #pragma unroll
    for (int g = 0; g < 2; ++g)
      *(f32x4*)&outp[(ty + 16 * i) * 128 + g * 64 + tx * 4] = acc[i][g];
}

// ---------------- in-place EXCLUSIVE prefix over superchunks ----------------
__global__ void skv_prefix(float* __restrict__ SKV) {
  const int e = blockIdx.x * 256 + threadIdx.x;
  float* p = SKV + (size_t)(blockIdx.z * H_ + blockIdx.y) * NSC * 16384 + e;
  float s = 0.f;
  #pragma unroll
  for (int sc = 0; sc < NSC; ++sc) {
    const float x = p[(size_t)sc * 16384];
    p[(size_t)sc * 16384] = s;
    s += x;
  }
}

// ---------------- fused chunked linear attention + RMSNorm (round-3 PROVEN, VALU) ----------------
__global__ __launch_bounds__(512, 1) void fused_attn(
    const float* PQ, const float* PK, const float* V,
    const float* __restrict__ SKVp, const float* __restrict__ rmsw, float* O)
{
  __shared__ __align__(16) float sS [128 * 128];
  __shared__ __align__(16) float sQt[128 * 64];
  __shared__ __align__(16) float sKt[128 * 64];
  __shared__ __align__(16) float sV [64 * 128];

  const int tid  = threadIdx.x;
  const int lane = tid & 63;
  const int tx = tid & 15, ty = tid >> 4;        // ty 0..31
  const int sc = blockIdx.x, h = blockIdx.y, b = blockIdx.z;
  const size_t R0 = (size_t)b * T_ + sc * 512;
  const float qscale = 0.08838834764831843f;     // 128^-0.5

  f32x4 rw[2];
  #pragma unroll
  for (int g = 0; g < 2; ++g) rw[g] = *(const f32x4*)&rmsw[g * 64 + tx * 4];

  // S init from prefixed SKV (exclusive superchunk state)
  {
    const float* slab = SKVp + ((size_t)(b * H_ + h) * NSC + sc) * 16384;
    for (int i = tid; i < 4096; i += 512)
      *(f32x4*)&sS[i * 4] = *(const f32x4*)&slab[i * 4];
  }
  __syncthreads();

  const int cst = tid & 63;        // staging column (= lane -> conflict-free writes)
  const int kq  = tid >> 6;        // staging k-quad: k in [kq*16, kq*16+16)

  for (int m = 0; m < NCHUNK; ++m) {
    const size_t rbase = R0 + m * 64;

    // stage q (scaled) and k, transposed [k][c]
    {
      const float* qp = PQ + (rbase + cst) * D_ + h * DH + kq * 16;
      const float* kp = PK + (rbase + cst) * D_ + h * DH + kq * 16;
      #pragma unroll
      for (int t = 0; t < 4; ++t) {
        const f32x4 qv = *(const f32x4*)(qp + t * 4);
        const f32x4 kv = *(const f32x4*)(kp + t * 4);
        #pragma unroll
        for (int e = 0; e < 4; ++e) {
          const int k = kq * 16 + t * 4 + e;
          sQt[k * 64 + cst] = qv[e] * qscale;
          sKt[k * 64 + cst] = kv[e];
        }
      }
    }
    // stage v natural [c][v]
    for (int i = tid; i < 2048; i += 512) {
      const int idx = i * 4;
      const int c2 = idx >> 7, v0 = idx & 127;
      *(f32x4*)&sV[idx] = *(const f32x4*)&V[(rbase + c2) * D_ + h * DH + v0];
    }
    __syncthreads();

    // phase A: a[i][j] = A[c = ty*2+i][s = tx*4+j]
    float a[2][4] = {};
    for (int k = 0; k < 128; ++k) {
      const float2 q2 = *(const float2*)&sQt[k * 64 + ty * 2];
      const f32x4  k4 = *(const f32x4*)&sKt[k * 64 + tx * 4];
      #pragma unroll
      for (int j = 0; j < 4; ++j) {
        a[0][j] = fmaf(q2.x, k4[j], a[0][j]);
        a[1][j] = fmaf(q2.y, k4[j], a[1][j]);
      }
    }
    #pragma unroll
    for (int i = 0; i < 2; ++i)
      #pragma unroll
      for (int j = 0; j < 4; ++j)
        if (tx * 4 + j > ty * 2 + i) a[i][j] = 0.f;

    float o[2][2][4] = {};   // [i][g][j]: row c=ty*2+i, col v=g*64+tx*4+j

    // o = A @ v  (A broadcast across the 16-lane row group via shfl)
    for (int tq = 0; tq < 16; ++tq) {
      const int src = (lane & 48) | tq;
      f32x4 vv[4][2];
      #pragma unroll
      for (int j = 0; j < 4; ++j)
        #pragma unroll
        for (int g = 0; g < 2; ++g)
          vv[j][g] = *(const f32x4*)&sV[(tq * 4 + j) * 128 + g * 64 + tx * 4];
      #pragma unroll
      for (int i = 0; i < 2; ++i) {
        float av[4];
        #pragma unroll
        for (int j = 0; j < 4; ++j) av[j] = __shfl(a[i][j], src);
        #pragma unroll
        for (int j = 0; j < 4; ++j)
          #pragma unroll
          for (int g = 0; g < 2; ++g)
            #pragma unroll
            for (int jj = 0; jj < 4; ++jj)
              o[i][g][jj] = fmaf(av[j], vv[j][g][jj], o[i][g][jj]);
      }
    }

    // o += q @ S_excl
    for (int k = 0; k < 128; ++k) {
      const float2 q2 = *(const float2*)&sQt[k * 64 + ty * 2];
      #pragma unroll
      for (int g = 0; g < 2; ++g) {
        const f32x4 sv = *(const f32x4*)&sS[k * 128 + g * 64 + tx * 4];
        #pragma unroll
        for (int j = 0; j < 4; ++j) {
          o[0][g][j] = fmaf(q2.x, sv[j], o[0][g][j]);
          o[1][g][j] = fmaf(q2.y, sv[j], o[1][g][j]);
        }
      }
    }
    __syncthreads();     // all S reads complete before update

    // S += k^T @ v  (thread owns k = ty+32i, v = g*64+tx*4+j)
    {
      f32x4 Sacc[4][2];
      #pragma unroll
      for (int i = 0; i < 4; ++i)
        #pragma unroll
        for (int g = 0; g < 2; ++g)
          Sacc[i][g] = *(const f32x4*)&sS[(ty + 32 * i) * 128 + g * 64 + tx * 4];
      for (int c = 0; c < 64; ++c) {
        f32x4 vvg[2];
        #pragma unroll
        for (int g = 0; g < 2; ++g)
          vvg[g] = *(const f32x4*)&sV[c * 128 + g * 64 + tx * 4];
        float kc[4];
        #pragma unroll
        for (int i = 0; i < 4; ++i) kc[i] = sKt[(ty + 32 * i) * 64 + c];
        #pragma unroll
        for (int i = 0; i < 4; ++i)
          #pragma unroll
          for (int g = 0; g < 2; ++g)
            #pragma unroll
            for (int j = 0; j < 4; ++j)
              Sacc[i][g][j] = fmaf(kc[i], vvg[g][j], Sacc[i][g][j]);
      }
      #pragma unroll
      for (int i = 0; i < 4; ++i)
        #pragma unroll
        for (int g = 0; g < 2; ++g)
          *(f32x4*)&sS[(ty + 32 * i) * 128 + g * 64 + tx * 4] = Sacc[i][g];
    }

    // RMSNorm over 128 cols (16 tx lanes per row) + in-place write
    #pragma unroll
    for (int i = 0; i < 2; ++i) {
      float ss = 0.f;
      #pragma unroll
      for (int g = 0; g < 2; ++g)
        #pragma unroll
        for (int j = 0; j < 4; ++j) ss += o[i][g][j] * o[i][g][j];
      ss += __shfl_xor(ss, 1); ss += __shfl_xor(ss, 2);
      ss += __shfl_xor(ss, 4); ss += __shfl_xor(ss, 8);
      const float inv = 1.f / sqrtf(ss * (1.f / 128.f) + 1e-5f);
      #pragma unroll
      for (int g = 0; g < 2; ++g) {
        f32x4 ov;
        #pragma unroll
        for (int j = 0; j < 4; ++j) ov[j] = o[i][g][j] * inv * rw[g][j];
        *(f32x4*)&O[(rbase + ty * 2 + i) * D_ + h * DH + g * 64 + tx * 4] = ov;
      }
    }
    __syncthreads();     // protect next chunk's staging
  }
}

// ---------------- host launch ----------------
extern "C" void kernel_launch(void* const* d_in, const int* in_sizes, int n_in,
                              void* d_out, int out_size, void* d_ws, size_t ws_size,
                              hipStream_t stream) {
  const float* hs = (const float*)d_in[0];
  const float* wsrc[4] = {(const float*)d_in[2], (const float*)d_in[3],
                          (const float*)d_in[4], (const float*)d_in[5]};  // q_w,k_w,v_w,o_w
  const float* fmq_w1 = (const float*)d_in[6];
  const float* fmq_b1 = (const float*)d_in[7];
  const float* fmq_w2 = (const float*)d_in[8];
  const float* fmq_b2 = (const float*)d_in[9];
  const float* fmk_w1 = (const float*)d_in[10];
  const float* fmk_b1 = (const float*)d_in[11];
  const float* fmk_w2 = (const float*)d_in[12];
  const float* fmk_b2 = (const float*)d_in[13];
  const float* rmsw   = (const float*)d_in[14];
  float* out = (float*)d_out;

  // workspace map — 160 MB (proven):
  //  [0,64)    q -> phi_q -> onorm (in-place)  f32
  //  [64,128)  k -> phi_k (in-place)           f32
  //  [128,144) big-weight bf16 hi/lo (4 x 4MB)
  //  [144,160) SKV superchunk totals (16 MB); first 256KB transiently holds the
  //            fm-weight concat splits (consumed before skv_kernel writes).
  // v lives in d_out (dead before the final GEMM overwrites it).
  char* ws = (char*)d_ws;
  const size_t MB = 1ull << 20;
  float* q = (float*)ws;
  float* k = (float*)(ws + 64 * MB);
  __hip_bfloat16* w_h[4]; __hip_bfloat16* w_l[4];
  for (int i = 0; i < 4; ++i) {
    w_h[i] = (__hip_bfloat16*)(ws + 128 * MB + (size_t)i * 4 * MB);
    w_l[i] = (__hip_bfloat16*)(ws + 128 * MB + (size_t)i * 4 * MB + 2 * MB);
  }
  float* SKV = (float*)(ws + 144 * MB);
  __hip_bfloat16* wcq_h = (__hip_bfloat16*)(ws + 144 * MB);
  __hip_bfloat16* wcq_l = (__hip_bfloat16*)(ws + 144 * MB + 64 * 1024);
  __hip_bfloat16* wck_h = (__hip_bfloat16*)(ws + 144 * MB + 128 * 1024);
  __hip_bfloat16* wck_l = (__hip_bfloat16*)(ws + 144 * MB + 192 * 1024);
  float* v = (float*)d_out;

  // 1) weight splits
  for (int i = 0; i < 4; ++i)
    split_hl<<<512, 256, 0, stream>>>(wsrc[i], w_h[i], w_l[i], D_ * D_);
  split_cat<<<128, 256, 0, stream>>>(fmq_w1, fmq_w2, wcq_h, wcq_l);
  split_cat<<<128, 256, 0, stream>>>(fmk_w1, fmk_w2, wck_h, wck_l);

  // 2) q/k/v projections
  dim3 gg(RTOT / 128, D_ / 128);
  gemm_f32a<<<gg, 256, 0, stream>>>(hs, w_h[0], w_l[0], q, RTOT, D_, D_);
  gemm_f32a<<<gg, 256, 0, stream>>>(hs, w_h[1], w_l[1], k, RTOT, D_, D_);
  gemm_f32a<<<gg, 256, 0, stream>>>(hs, w_h[2], w_l[2], v, RTOT, D_, D_);

  // 3) Hadamard feature maps (MFMA, in-place)
  featuremap2<<<dim3(RTOT / 128, H_), 512, 0, stream>>>(q, wcq_h, wcq_l, fmq_b1, fmq_b2);
  featuremap2<<<dim3(RTOT / 128, H_), 512, 0, stream>>>(k, wck_h, wck_l, fmk_b1, fmk_b2);

  // 4) superchunk kv totals + exclusive prefix
  skv_kernel<<<dim3(NSC, H_, B_), 256, 0, stream>>>(k, v, SKV);
  skv_prefix<<<dim3(64, H_, B_), 256, 0, stream>>>(SKV);

  // 5) fused chunked attention + RMSNorm (round-3 proven VALU version, in-place over q)
  fused_attn<<<dim3(NSC, H_, B_), 512, 0, stream>>>(q, k, v, SKV, rmsw, q);

  // 6) output projection
  gemm_f32a<<<gg, 256, 0, stream>>>(q, w_h[3], w_l[3], out, RTOT, D_, D_);
}